// Round 10
// baseline (1639.878 us; speedup 1.0000x reference)
//
#include <hip/hip_runtime.h>
#include <math.h>

#define TT 1024
#define DD 128
#define UU 64

__device__ __forceinline__ float sigm(float x) {
    return __builtin_amdgcn_rcpf(1.0f + __expf(-x));
}
__device__ __forceinline__ float tanhfast(float x) {
    float e = __expf(2.0f * x);
    return fmaf(-2.0f, __builtin_amdgcn_rcpf(e + 1.0f), 1.0f);
}

// DPP-based full-wave (64-lane) sum, result broadcast via readlane(63).
template<int CTRL>
__device__ __forceinline__ float dpp_add(float v) {
    return v + __int_as_float(__builtin_amdgcn_update_dpp(
        0, __float_as_int(v), CTRL, 0xf, 0xf, true));
}
__device__ __forceinline__ float wave_red_sum(float v) {
    v = dpp_add<0x111>(v);   // row_shr:1
    v = dpp_add<0x112>(v);   // row_shr:2
    v = dpp_add<0x114>(v);   // row_shr:4
    v = dpp_add<0x118>(v);   // row_shr:8
    v = dpp_add<0x142>(v);   // row_bcast:15
    v = dpp_add<0x143>(v);   // row_bcast:31
    return __int_as_float(__builtin_amdgcn_readlane(__float_as_int(v), 63));
}

// ---------------- AGPR weight stash -----------------------------------------
// R9 post-mortem: the RA refuses to keep 64 loop-invariant weight floats in
// VGPRs (pressure-aware LICM leaves the loads in the loop -> 196 KB/CU/step of
// L2 reads ~= the whole step time). AGPRs are a free register file here (no
// MFMA in this kernel). "=a" constraints make the values AGPR-resident SSA
// values; volatile reads keep the per-use copies inside the loop.
#define AW_DECLS \
    float aw0,aw1,aw2,aw3,aw4,aw5,aw6,aw7,aw8,aw9,aw10,aw11,aw12,aw13,aw14,aw15, \
          aw16,aw17,aw18,aw19,aw20,aw21,aw22,aw23,aw24,aw25,aw26,aw27,aw28,aw29,aw30,aw31, \
          aw32,aw33,aw34,aw35,aw36,aw37,aw38,aw39,aw40,aw41,aw42,aw43,aw44,aw45,aw46,aw47, \
          aw48,aw49,aw50,aw51,aw52,aw53,aw54,aw55,aw56,aw57,aw58,aw59,aw60,aw61,aw62,aw63;

#define AW_SET(i, EXPR) { float _t = (EXPR); \
    asm volatile("v_accvgpr_write_b32 %0, %1" : "=a"(aw##i) : "v"(_t)); }

#define AW_STASH(M) \
    AW_SET(0,M(0))   AW_SET(1,M(1))   AW_SET(2,M(2))   AW_SET(3,M(3))   \
    AW_SET(4,M(4))   AW_SET(5,M(5))   AW_SET(6,M(6))   AW_SET(7,M(7))   \
    AW_SET(8,M(8))   AW_SET(9,M(9))   AW_SET(10,M(10)) AW_SET(11,M(11)) \
    AW_SET(12,M(12)) AW_SET(13,M(13)) AW_SET(14,M(14)) AW_SET(15,M(15)) \
    AW_SET(16,M(16)) AW_SET(17,M(17)) AW_SET(18,M(18)) AW_SET(19,M(19)) \
    AW_SET(20,M(20)) AW_SET(21,M(21)) AW_SET(22,M(22)) AW_SET(23,M(23)) \
    AW_SET(24,M(24)) AW_SET(25,M(25)) AW_SET(26,M(26)) AW_SET(27,M(27)) \
    AW_SET(28,M(28)) AW_SET(29,M(29)) AW_SET(30,M(30)) AW_SET(31,M(31)) \
    AW_SET(32,M(32)) AW_SET(33,M(33)) AW_SET(34,M(34)) AW_SET(35,M(35)) \
    AW_SET(36,M(36)) AW_SET(37,M(37)) AW_SET(38,M(38)) AW_SET(39,M(39)) \
    AW_SET(40,M(40)) AW_SET(41,M(41)) AW_SET(42,M(42)) AW_SET(43,M(43)) \
    AW_SET(44,M(44)) AW_SET(45,M(45)) AW_SET(46,M(46)) AW_SET(47,M(47)) \
    AW_SET(48,M(48)) AW_SET(49,M(49)) AW_SET(50,M(50)) AW_SET(51,M(51)) \
    AW_SET(52,M(52)) AW_SET(53,M(53)) AW_SET(54,M(54)) AW_SET(55,M(55)) \
    AW_SET(56,M(56)) AW_SET(57,M(57)) AW_SET(58,M(58)) AW_SET(59,M(59)) \
    AW_SET(60,M(60)) AW_SET(61,M(61)) AW_SET(62,M(62)) AW_SET(63,M(63))

#define AW_GET(i) __extension__({ float _g; \
    asm volatile("v_accvgpr_read_b32 %0, %1" : "=v"(_g) : "a"(aw##i)); _g; })

#define DOTA_CH(k, i0, i1, i2, i3) { float4 _hv = _v4[k]; \
    _a0 = fmaf(_hv.x, AW_GET(i0), _a0); \
    _a1 = fmaf(_hv.y, AW_GET(i1), _a1); \
    _a2 = fmaf(_hv.z, AW_GET(i2), _a2); \
    _a3 = fmaf(_hv.w, AW_GET(i3), _a3); }

// 64-float dot: LDS vector (broadcast float4 reads) x AGPR-resident weights.
#define DOTA(res, vptr) do { \
    const float4* _v4 = (const float4*)(vptr); \
    float _a0 = 0.f, _a1 = 0.f, _a2 = 0.f, _a3 = 0.f; \
    DOTA_CH(0,0,1,2,3)      DOTA_CH(1,4,5,6,7)      DOTA_CH(2,8,9,10,11)    DOTA_CH(3,12,13,14,15)  \
    DOTA_CH(4,16,17,18,19)  DOTA_CH(5,20,21,22,23)  DOTA_CH(6,24,25,26,27)  DOTA_CH(7,28,29,30,31)  \
    DOTA_CH(8,32,33,34,35)  DOTA_CH(9,36,37,38,39)  DOTA_CH(10,40,41,42,43) DOTA_CH(11,44,45,46,47) \
    DOTA_CH(12,48,49,50,51) DOTA_CH(13,52,53,54,55) DOTA_CH(14,56,57,58,59) DOTA_CH(15,60,61,62,63) \
    res = (_a0 + _a1) + (_a2 + _a3); } while (0)

// ================= x-part GEMM (round-4 proven version) ======================
// z1x[r, col] = obss[b, t0+tloc, :] @ W1[0:128, col]
__global__ __launch_bounds__(256, 1)
void xgemm(const float* __restrict__ obss, const float* __restrict__ W1,
           float* __restrict__ z1x, int t0, int chsh)
{
    const int tid = threadIdx.x;
    const int CH = 1 << chsh;
    __shared__ __align__(16) float xs[64 * DD];

    const int rbase = blockIdx.x * 64;
    for (int i = tid; i < 64 * (DD / 4); i += 256) {
        int rr = i >> 5;
        int k4 = i & 31;
        int r  = rbase + rr;
        int b  = r >> chsh;
        int tl = r & (CH - 1);
        ((float4*)xs)[rr * 32 + k4] =
            ((const float4*)(obss + ((size_t)b * TT + t0 + tl) * DD))[k4];
    }

    float w[DD];
    #pragma unroll
    for (int k = 0; k < DD; ++k) w[k] = W1[k * 256 + tid];
    __syncthreads();

    for (int rr = 0; rr < 64; rr += 2) {
        float a0=0,a1=0,a2=0,a3=0, b0=0,b1=0,b2=0,b3=0;
        const float4* x0 = (const float4*)(xs + rr * DD);
        const float4* x1 = (const float4*)(xs + (rr + 1) * DD);
        #pragma unroll
        for (int k4 = 0; k4 < DD / 4; ++k4) {
            float4 xv = x0[k4], yv = x1[k4];
            a0 = fmaf(xv.x, w[4*k4+0], a0);
            a1 = fmaf(xv.y, w[4*k4+1], a1);
            a2 = fmaf(xv.z, w[4*k4+2], a2);
            a3 = fmaf(xv.w, w[4*k4+3], a3);
            b0 = fmaf(yv.x, w[4*k4+0], b0);
            b1 = fmaf(yv.y, w[4*k4+1], b1);
            b2 = fmaf(yv.z, w[4*k4+2], b2);
            b3 = fmaf(yv.w, w[4*k4+3], b3);
        }
        size_t r = (size_t)rbase + rr;
        z1x[r * 256 + tid]       = (a0 + a1) + (a2 + a3);
        z1x[(r + 1) * 256 + tid] = (b0 + b1) + (b2 + b3);
    }
}

// ============ recurrent kernel: 3-group pipeline, 768 threads ================
// G0 (waves 0-3):  layer 1 at step n.  w1h in AGPRs.
// G1 (waves 4-7):  z2x = h1(n-1) @ W2x (p1) + output projection (p2). w2x AGPRs.
// G2 (waves 8-11): layer 2 at step n-2: cell2+z2h-dot in p1, z2-LN in p2. w2h AGPRs.
__global__ __launch_bounds__(768) __attribute__((amdgpu_waves_per_eu(3, 3)))
void lstm_rec(const float* __restrict__ z1x,
              const float* __restrict__ W1, const float* __restrict__ W2,
              const float* __restrict__ gamma1, const float* __restrict__ beta1,
              const float* __restrict__ gc1, const float* __restrict__ bc1,
              const float* __restrict__ gamma2, const float* __restrict__ beta2,
              const float* __restrict__ gc2, const float* __restrict__ bc2,
              const float* __restrict__ Wd, const float* __restrict__ bd,
              float* __restrict__ out, float* __restrict__ state,
              int t0, int nsteps)
{
    const int tid  = threadIdx.x;
    const int b    = blockIdx.x;
    const int gid  = tid >> 8;        // 0, 1, 2
    const int stid = tid & 255;
    const int lane = stid & 63;
    const int wav  = stid >> 6;

    __shared__ __align__(16) float zsA[256], zsB[256], z2xs[256];
    __shared__ __align__(16) float h1ring[2][UU];
    __shared__ __align__(16) float h1p[4][UU], h2p[4][UU];
    __shared__ __align__(16) float h2hist[32 * 65];
    __shared__ __align__(16) float wds[UU * 16];
    __shared__ float bds[16];

    float* st = state + (size_t)b * 256;
    const int NS = nsteps;

    if (gid == 0) {
        // ============================ G0: LAYER 1 ===========================
        AW_DECLS
        #define W1H_EXPR(k) (W1[(DD + (k)) * 256 + stid])
        AW_STASH(W1H_EXPR)
        const float g1 = gamma1[stid], bb1 = beta1[stid];
        const float gcl = gc1[lane],  bcl = bc1[lane];

        float c1, h1v = 0.f;
        if (t0 == 0) { c1 = 0.f; h1p[wav][lane] = 0.f; }
        else         { c1 = st[lane]; h1v = st[64 + lane]; h1p[wav][lane] = h1v; }

        const float* zrow = z1x + (size_t)b * NS * 256;
        float zx = zrow[stid];
        __syncthreads();                       // init

        #pragma unroll 1
        for (int n = 0; n <= NS + 2; ++n) {
            float zxn = zx;
            if (n < NS) {
                int tnl = (n + 1 < NS) ? n + 1 : n;
                zxn = zrow[(size_t)tnl * 256 + stid];

                float zdot;
                DOTA(zdot, h1p[wav]);
                float z = zx + zdot;
                float s = wave_red_sum(z);
                float q = wave_red_sum(z * z);
                float mu  = s * (1.f/64.f);
                float var = q * (1.f/64.f) - mu * mu;
                float zn  = (z - mu) * __builtin_amdgcn_rsqf(var + 1e-12f) * g1 + bb1;
                zsA[stid] = (wav == 1) ? tanhfast(zn)
                          : (wav == 2) ? sigm(zn + 1.f)
                          :              sigm(zn);
            }
            __syncthreads();                   // B1
            if (n < NS) {
                float ai = zsA[lane],       aj = zsA[64 + lane];
                float af = zsA[128 + lane], ao = zsA[192 + lane];
                c1 = c1 * af + ai * aj;
                float cs = wave_red_sum(c1);
                float cq = wave_red_sum(c1 * c1);
                float cmu  = cs * (1.f/64.f);
                float cvar = cq * (1.f/64.f) - cmu * cmu;
                float cn   = (c1 - cmu) * __builtin_amdgcn_rsqf(cvar + 1e-12f) * gcl + bcl;
                h1v = tanhfast(cn) * ao;
                h1p[wav][lane] = h1v;
                if (wav == 0) h1ring[n & 1][lane] = h1v;
            }
            __syncthreads();                   // B2
            zx = zxn;
        }
        if (t0 + NS < TT && wav == 0) {
            st[lane]      = c1;
            st[64 + lane] = h1v;
        }
    } else if (gid == 1) {
        // ================= G1: z2x feed + output projection =================
        AW_DECLS
        #define W2X_EXPR(k) (W2[(k) * 256 + stid])
        AW_STASH(W2X_EXPR)
        for (int i = stid; i < UU * 16; i += 256) wds[i] = Wd[i];
        if (stid < 16) bds[stid] = bd[stid];
        __syncthreads();                       // init

        #pragma unroll 1
        for (int n = 0; n <= NS + 2; ++n) {
            if (n >= 1 && n <= NS) {
                float zxdot;
                DOTA(zxdot, h1ring[(n - 1) & 1]);
                z2xs[stid] = zxdot;
            }
            __syncthreads();                   // B1
            // projection for rows n-18 .. n-3 (slot (n-2)&31 written this
            // iteration is NOT in the read set; h2hist has 32 slots)
            if ((n & 15) == 2 && n >= 18) {
                int rloc = stid >> 4;
                int a    = stid & 15;
                int m    = n - 18 + rloc;          // row within chunk
                float o = bds[a];
                const float* hrow = &h2hist[(m & 31) * 65];
                #pragma unroll
                for (int k = 0; k < UU; ++k)
                    o = fmaf(hrow[k], wds[k * 16 + a], o);
                out[((size_t)b * TT + (t0 + m)) * 16 + a] = tanhfast(o);
            }
            __syncthreads();                   // B2
        }
    } else {
        // ============================ G2: LAYER 2 ===========================
        AW_DECLS
        #define W2H_EXPR(k) (W2[(UU + (k)) * 256 + stid])
        AW_STASH(W2H_EXPR)
        const float g2 = gamma2[stid], bb2 = beta2[stid];
        const float gcl = gc2[lane],  bcl = bc2[lane];

        float c2, h2v = 0.f;
        if (t0 == 0) { c2 = 0.f; h2p[wav][lane] = 0.f; }
        else         { c2 = st[128 + lane]; h2v = st[192 + lane]; h2p[wav][lane] = h2v; }
        // z2h = h2(prev)@W2h carried in-register (recomputed at chunk start)
        float z2h = 0.f;
        if (t0 != 0) { DOTA(z2h, h2p[wav]); }
        __syncthreads();                       // init

        #pragma unroll 1
        for (int n = 0; n <= NS + 2; ++n) {
            if (n >= 2 && n <= NS + 1) {
                // cell2 for step n-2 (zsB written p2(n-1), crosses B2)
                float ai = zsB[lane],       aj = zsB[64 + lane];
                float af = zsB[128 + lane], ao = zsB[192 + lane];
                c2 = c2 * af + ai * aj;
                float cs = wave_red_sum(c2);
                float cq = wave_red_sum(c2 * c2);
                float cmu  = cs * (1.f/64.f);
                float cvar = cq * (1.f/64.f) - cmu * cmu;
                float cn   = (c2 - cmu) * __builtin_amdgcn_rsqf(cvar + 1e-12f) * gcl + bcl;
                h2v = tanhfast(cn) * ao;
                h2p[wav][lane] = h2v;
                if (wav == 0) h2hist[((n - 2) & 31) * 65 + lane] = h2v;
                // z2h = h2(n-2) @ W2h for z2(n-1), assembled in p2 this iter
                DOTA(z2h, h2p[wav]);
            }
            __syncthreads();                   // B1
            if (n >= 1 && n <= NS) {
                // z2 for step n-1 (z2xs written G1 p1(n), crosses B1)
                float z2 = z2xs[stid] + z2h;
                float s2 = wave_red_sum(z2);
                float q2 = wave_red_sum(z2 * z2);
                float mu2  = s2 * (1.f/64.f);
                float var2 = q2 * (1.f/64.f) - mu2 * mu2;
                float zn2  = (z2 - mu2) * __builtin_amdgcn_rsqf(var2 + 1e-12f) * g2 + bb2;
                zsB[stid] = (wav == 1) ? tanhfast(zn2)
                          : (wav == 2) ? sigm(zn2 + 1.f)
                          :              sigm(zn2);
            }
            __syncthreads();                   // B2
        }
        if (t0 + NS < TT && wav == 0) {
            st[128 + lane] = c2;
            st[192 + lane] = h2v;
        }
    }
}

extern "C" void kernel_launch(void* const* d_in, const int* in_sizes, int n_in,
                              void* d_out, int out_size, void* d_ws, size_t ws_size,
                              hipStream_t stream) {
    (void)in_sizes; (void)n_in; (void)out_size;
    const float* obss   = (const float*)d_in[0];
    const float* W1     = (const float*)d_in[1];
    const float* gamma1 = (const float*)d_in[2];
    const float* beta1  = (const float*)d_in[3];
    const float* gc1    = (const float*)d_in[4];
    const float* bc1    = (const float*)d_in[5];
    const float* W2     = (const float*)d_in[6];
    const float* gamma2 = (const float*)d_in[7];
    const float* beta2  = (const float*)d_in[8];
    const float* gc2    = (const float*)d_in[9];
    const float* bc2    = (const float*)d_in[10];
    const float* Wd     = (const float*)d_in[11];
    const float* bd     = (const float*)d_in[12];
    float* out = (float*)d_out;

    float* state = (float*)d_ws;
    float* z1x   = (float*)((char*)d_ws + (size_t)256 * 256 * sizeof(float));

    int CH = 16;
    for (int c = TT; c >= 16; c >>= 1) {
        size_t need = (size_t)256 * c * 256 * sizeof(float)
                    + (size_t)256 * 256 * sizeof(float);
        if (need <= ws_size) { CH = c; break; }
    }
    int chsh = 31 - __builtin_clz((unsigned)CH);

    for (int t0 = 0; t0 < TT; t0 += CH) {
        xgemm<<<(256 * CH) / 64, 256, 0, stream>>>(obss, W1, z1x, t0, chsh);
        lstm_rec<<<256, 768, 0, stream>>>(z1x, W1, W2,
                                          gamma1, beta1, gc1, bc1,
                                          gamma2, beta2, gc2, bc2,
                                          Wd, bd, out, state, t0, CH);
    }
}